// Round 1
// baseline (741.537 us; speedup 1.0000x reference)
//
#include <hip/hip_runtime.h>
#include <cstdint>
#include <cstddef>

typedef unsigned short u16;
typedef __attribute__((ext_vector_type(8))) short short8;   // 8 x bf16 (4 VGPRs) MFMA A/B frag
typedef __attribute__((ext_vector_type(4))) short short4v;
typedef __attribute__((ext_vector_type(4))) float f32x4;    // MFMA C/D frag

#define NTOK 65536
#define HID 512
#define NVOCAB 1024

// ---------- bf16 helpers (raw-bit, RNE) ----------
__device__ __forceinline__ u16 f2bf(float f) {
  union { float f; uint32_t u; } v; v.f = f;
  uint32_t r = (v.u + 0x7FFFu + ((v.u >> 16) & 1u)) >> 16;
  return (u16)r;
}
__device__ __forceinline__ float bf2f(u16 b) {
  union { uint32_t u; float f; } v; v.u = ((uint32_t)b) << 16;
  return v.f;
}

// async global->LDS, 16B per lane; LDS dest = wave-uniform base + lane*16
__device__ __forceinline__ void gl_lds16(const u16* g, u16* l) {
  __builtin_amdgcn_global_load_lds(
      (const __attribute__((address_space(1))) uint32_t*)g,
      (__attribute__((address_space(3))) uint32_t*)l, 16, 0, 0);
}

// ---------- hash constants (precomputed from reference) ----------
__constant__ uint32_t P24[24] = {
  2654435761u, 2246822519u, 3266489917u, 2028178513u, 1220703125u,
  1610612741u, 805306457u, 402653189u, 3674653429u, 2860486313u,
  1073676287u, 2971215073u, 1500450271u, 3267000013u, 2654435789u,
  4049292737u, 2246822531u, 3266489927u, 2028178519u, 1220703133u,
  1610612743u, 805306459u, 402653191u, 3674653433u};
__constant__ unsigned char OFFS[32][3] = {
  {1,0,0},{2,0,0},{3,0,0},{4,0,0},{5,0,0},{6,0,0},{7,0,0},{8,0,0},
  {1,2,0},{2,3,0},{3,4,0},{1,3,0},{2,4,0},{1,4,0},{1,5,0},{2,5,0},
  {3,5,0},{1,6,0},{2,6,0},{1,7,0},
  {1,2,3},{1,2,4},{1,3,5},{2,3,4},{1,2,5},{1,3,4},{2,4,6},{1,4,7},
  {1,8,0},{1,9,0},{1,10,0},{1,11,0}};
__constant__ unsigned char PLEN[32] = {
  1,1,1,1,1,1,1,1, 2,2,2,2,2,2,2,2,2,2,2,2, 3,3,3,3,3,3,3,3, 2,2,2,2};

// ---------- weight fp32 -> bf16 (4 elems/thread) ----------
__global__ __launch_bounds__(256) void cvt_bf16(const float* __restrict__ src,
                                                u16* __restrict__ dst, int n) {
  int i = (blockIdx.x * 256 + threadIdx.x) * 4;
  if (i < n) {
    float4 f = *(const float4*)(src + i);
    short4v o;
    o[0] = (short)f2bf(f.x); o[1] = (short)f2bf(f.y);
    o[2] = (short)f2bf(f.z); o[3] = (short)f2bf(f.w);
    *(short4v*)(dst + i) = o;
  }
}

// ---------- features: byte-embed + 32 hash embeds -> [NTOK,512] bf16 ----------
// block = 256 threads = 8 tokens x 32 lanes
__global__ __launch_bounds__(256) void feat_kernel(
    const int* __restrict__ chars, const float* __restrict__ byte_embed,
    const float* __restrict__ hash_tables, u16* __restrict__ feat)
{
  const int tid = threadIdx.x;
  const int tl  = tid >> 5;        // token-local 0..7
  const int sub = tid & 31;        // segment / table id
  const size_t t = (size_t)blockIdx.x * 8 + tl;
  const int s = (int)(t & 2047);   // position within sequence
  const int c = chars[t];

  // byte embedding: 8 consecutive floats -> bf16
  {
    const float* src = byte_embed + ((size_t)c << 8) + (sub << 3);
    float4 f0 = ((const float4*)src)[0];
    float4 f1 = ((const float4*)src)[1];
    short8 o;
    o[0]=(short)f2bf(f0.x); o[1]=(short)f2bf(f0.y); o[2]=(short)f2bf(f0.z); o[3]=(short)f2bf(f0.w);
    o[4]=(short)f2bf(f1.x); o[5]=(short)f2bf(f1.y); o[6]=(short)f2bf(f1.z); o[7]=(short)f2bf(f1.w);
    *(short8*)(feat + t * HID + (sub << 3)) = o;
  }

  // hash table `sub`
  {
    const int i = sub;
    const int pl = (int)PLEN[i];
    long long h = 0;
    #pragma unroll
    for (int k = 0; k < 3; ++k) {
      if (k < pl) {
        const int off = (int)OFFS[i][k];
        const long long tok = (s >= off) ? (long long)chars[t - off] : 0ll;
        h ^= tok * (long long)P24[(3 * i + k) % 24];   // tok<2^10, prime<2^32: no ovf
      }
    }
    const int idx_lo = (int)(h & 4095);                // h >= 0
    const long long sp = (long long)P24[(3 * i + pl) % 24];
    // int64 wrap-around multiply (matches jax int64 semantics), arithmetic >>16
    const long long prod = (long long)((unsigned long long)h * (unsigned long long)sp);
    const long long h2 = h ^ (prod >> 16);
    const int idx_hi = (int)(h2 & 4095);               // floored mod == & for pow2
    const float frac = ((float)(int)((h >> 3) & 255) / 255.0f) * 0.4f;
    const float om = 1.0f - frac;

    const float* plo = hash_tables + (((size_t)i << 12) + (size_t)idx_lo) * 8;
    const float* phi = hash_tables + (((size_t)i << 12) + (size_t)idx_hi) * 8;
    float4 a0 = ((const float4*)plo)[0], a1 = ((const float4*)plo)[1];
    float4 b0 = ((const float4*)phi)[0], b1 = ((const float4*)phi)[1];
    short8 o;
    o[0]=(short)f2bf(a0.x*om + b0.x*frac); o[1]=(short)f2bf(a0.y*om + b0.y*frac);
    o[2]=(short)f2bf(a0.z*om + b0.z*frac); o[3]=(short)f2bf(a0.w*om + b0.w*frac);
    o[4]=(short)f2bf(a1.x*om + b1.x*frac); o[5]=(short)f2bf(a1.y*om + b1.y*frac);
    o[6]=(short)f2bf(a1.z*om + b1.z*frac); o[7]=(short)f2bf(a1.w*om + b1.w*frac);
    *(short8*)(feat + t * HID + 256 + (i << 3)) = o;
  }
}

// ---------- bf16 GEMM, 256x256 tile / BK=64 / 8 waves, 8-phase-style schedule ----
// C[M,N] = act(A[M,K] @ Bt[N,K]^T + bias) (+resid)
// Techniques (guide T1..T5): XCD-bijective block swizzle; st-swizzled LDS
// (byte ^= (row&7)<<4, applied on BOTH stage-source and ds_read — involution);
// counted vmcnt(8) once per K-tile (never 0 in steady state); per-phase
// barriers + s_setprio(1) around each 16-MFMA quadrant cluster.
// LDS: 2 dbuf x {A,B} x 256x64 bf16 = 128 KiB -> 1 block/CU, 8 waves.
template<bool RELU, bool RESID, bool F32OUT>
__global__ __launch_bounds__(512, 2)
void gemm256(const u16* __restrict__ A, const u16* __restrict__ Bt,
             const float* __restrict__ bias, const u16* __restrict__ resid,
             void* __restrict__ outp, int M, int N, int K)
{
  __shared__ __align__(16) u16 lds[2][2][256 * 64];

  const int tid  = threadIdx.x;
  const int w    = tid >> 6;       // wave 0..7
  const int lane = tid & 63;

  // XCD-aware bijective swizzle (both grids have nwg % 8 == 0)
  const int gx  = gridDim.x;
  const int nwg = gx * gridDim.y;
  const int bid = blockIdx.y * gx + blockIdx.x;
  const int cpx = nwg >> 3;
  const int wk  = (bid & 7) * cpx + (bid >> 3);
  const int n0  = (wk % gx) << 8;
  const int m0  = (wk / gx) << 8;

  const int wr   = w >> 2;         // 0..1 : M half of tile (128 rows)
  const int wcol = w & 3;          // 0..3 : N quarter (64 cols)

  // ---- staging geometry: per load-instr a wave covers 8 rows x 64 cols ----
  // lane l -> row w*8 + (l>>3), 16B chunk (l&7); source col pre-swizzled so a
  // LINEAR LDS dest + swizzled ds_read form a consistent involution.
  const int srow = (w << 3) + (lane >> 3);               // 0..63
  const int scol = (((lane & 7) ^ (lane >> 3)) << 3);    // elems, pre-swizzled
  const u16* gA = A  + (size_t)(m0 + srow) * K + scol;
  const u16* gB = Bt + (size_t)(n0 + srow) * K + scol;

  auto stage = [&](int buf, int kt) {
    const size_t ko = (size_t)kt << 6;
    #pragma unroll
    for (int j = 0; j < 4; ++j)
      gl_lds16(gA + (size_t)(j << 6) * K + ko, &lds[buf][0][((j << 6) + (w << 3)) << 6]);
    #pragma unroll
    for (int j = 0; j < 4; ++j)
      gl_lds16(gB + (size_t)(j << 6) * K + ko, &lds[buf][1][((j << 6) + (w << 3)) << 6]);
  };

  // ---- fragment read addressing (swizzled) ----
  const int rlo = lane & 15;
  const int q8  = (lane >> 4) << 3;    // 16B quarter within frag k-span
  const int sx  = (lane & 7) << 3;     // swizzle XOR (elems)

  auto rdA = [&](int buf, int half, int mi, int kk) -> short8 {
    const int row = (wr << 7) + (half << 6) + (mi << 4) + rlo;
    const int col = ((kk << 5) + q8) ^ sx;
    return *(const short8*)&lds[buf][0][row * 64 + col];
  };
  auto rdB = [&](int buf, int half, int ni, int kk) -> short8 {
    const int row = (wcol << 6) + (half << 5) + (ni << 4) + rlo;
    const int col = ((kk << 5) + q8) ^ sx;
    return *(const short8*)&lds[buf][1][row * 64 + col];
  };

  f32x4 acc[8][4];
  #pragma unroll
  for (int i = 0; i < 8; ++i)
    #pragma unroll
    for (int j = 0; j < 4; ++j) acc[i][j] = (f32x4){0.f, 0.f, 0.f, 0.f};

  const int NT = K >> 6;   // 8 for K=512
  stage(0, 0);
  stage(1, 1);

  for (int kt = 0; kt < NT; ++kt) {
    const int cur = kt & 1;
    // tile-kt loads landed for THIS wave (next tile's 8 stay in flight)
    if (kt + 1 < NT) asm volatile("s_waitcnt vmcnt(8)" ::: "memory");
    else             asm volatile("s_waitcnt vmcnt(0)" ::: "memory");
    __builtin_amdgcn_s_barrier();   // ... and for every wave

    short8 aR[4][2], b0[2][2], b1[2][2];

    // -- phase 0: quadrant (M0,N0); reads A-half0 (8) + B-half0 (4)
    #pragma unroll
    for (int mi = 0; mi < 4; ++mi) {
      aR[mi][0] = rdA(cur, 0, mi, 0);
      aR[mi][1] = rdA(cur, 0, mi, 1);
    }
    #pragma unroll
    for (int ni = 0; ni < 2; ++ni) {
      b0[ni][0] = rdB(cur, 0, ni, 0);
      b0[ni][1] = rdB(cur, 0, ni, 1);
    }
    __builtin_amdgcn_s_barrier();
    asm volatile("s_waitcnt lgkmcnt(0)" ::: "memory");
    __builtin_amdgcn_sched_barrier(0);
    __builtin_amdgcn_s_setprio(1);
    #pragma unroll
    for (int mi = 0; mi < 4; ++mi)
      #pragma unroll
      for (int ni = 0; ni < 2; ++ni)
        #pragma unroll
        for (int kk = 0; kk < 2; ++kk)
          acc[mi][ni] = __builtin_amdgcn_mfma_f32_16x16x32_bf16(aR[mi][kk], b0[ni][kk], acc[mi][ni], 0, 0, 0);
    __builtin_amdgcn_s_setprio(0);
    __builtin_amdgcn_s_barrier();

    // -- phase 1: quadrant (M0,N1); reads B-half1 (4)
    #pragma unroll
    for (int ni = 0; ni < 2; ++ni) {
      b1[ni][0] = rdB(cur, 1, ni, 0);
      b1[ni][1] = rdB(cur, 1, ni, 1);
    }
    __builtin_amdgcn_s_barrier();
    asm volatile("s_waitcnt lgkmcnt(0)" ::: "memory");
    __builtin_amdgcn_sched_barrier(0);
    __builtin_amdgcn_s_setprio(1);
    #pragma unroll
    for (int mi = 0; mi < 4; ++mi)
      #pragma unroll
      for (int ni = 0; ni < 2; ++ni)
        #pragma unroll
        for (int kk = 0; kk < 2; ++kk)
          acc[mi][2 + ni] = __builtin_amdgcn_mfma_f32_16x16x32_bf16(aR[mi][kk], b1[ni][kk], acc[mi][2 + ni], 0, 0, 0);
    __builtin_amdgcn_s_setprio(0);
    __builtin_amdgcn_s_barrier();

    // -- phase 2: quadrant (M1,N0); reads A-half1 (8), b0 still live
    #pragma unroll
    for (int mi = 0; mi < 4; ++mi) {
      aR[mi][0] = rdA(cur, 1, mi, 0);
      aR[mi][1] = rdA(cur, 1, mi, 1);
    }
    __builtin_amdgcn_s_barrier();
    asm volatile("s_waitcnt lgkmcnt(0)" ::: "memory");
    __builtin_amdgcn_sched_barrier(0);
    __builtin_amdgcn_s_setprio(1);
    #pragma unroll
    for (int mi = 0; mi < 4; ++mi)
      #pragma unroll
      for (int ni = 0; ni < 2; ++ni)
        #pragma unroll
        for (int kk = 0; kk < 2; ++kk)
          acc[4 + mi][ni] = __builtin_amdgcn_mfma_f32_16x16x32_bf16(aR[mi][kk], b0[ni][kk], acc[4 + mi][ni], 0, 0, 0);
    __builtin_amdgcn_s_setprio(0);
    __builtin_amdgcn_s_barrier();

    // -- phase 3: quadrant (M1,N1); no reads
    __builtin_amdgcn_s_setprio(1);
    #pragma unroll
    for (int mi = 0; mi < 4; ++mi)
      #pragma unroll
      for (int ni = 0; ni < 2; ++ni)
        #pragma unroll
        for (int kk = 0; kk < 2; ++kk)
          acc[4 + mi][2 + ni] = __builtin_amdgcn_mfma_f32_16x16x32_bf16(aR[mi][kk], b1[ni][kk], acc[4 + mi][2 + ni], 0, 0, 0);
    __builtin_amdgcn_s_setprio(0);
    __builtin_amdgcn_s_barrier();   // all waves done reading buf[cur]

    // restage freed buffer for tile kt+2 (8 loads -> vmcnt(8) at next entry)
    if (kt + 2 < NT) stage(cur, kt + 2);
  }

  // ---- epilogue: C/D layout col=lane&15, row=(lane>>4)*4+r ----
  const int er = (lane >> 4) << 2;
  const int ec = lane & 15;
  #pragma unroll
  for (int ni = 0; ni < 4; ++ni) {
    const int col = n0 + (wcol << 6) + (ni << 4) + ec;
    const float bs = bias[col];
    #pragma unroll
    for (int mi = 0; mi < 8; ++mi) {
      #pragma unroll
      for (int r = 0; r < 4; ++r) {
        const int row = m0 + (wr << 7) + (mi << 4) + er + r;
        float v = acc[mi][ni][r] + bs;
        if (RELU) v = fmaxf(v, 0.0f);
        if (RESID) v += bf2f(resid[(size_t)row * N + col]);
        if (F32OUT) ((float*)outp)[(size_t)row * N + col] = v;
        else        ((u16*)  outp)[(size_t)row * N + col] = f2bf(v);
      }
    }
  }
}

extern "C" void kernel_launch(void* const* d_in, const int* in_sizes, int n_in,
                              void* d_out, int out_size, void* d_ws, size_t ws_size,
                              hipStream_t stream) {
  const int*   chars      = (const int*)  d_in[0];
  const float* byte_embed = (const float*)d_in[1];
  const float* hash_tabs  = (const float*)d_in[2];
  const float* w_in       = (const float*)d_in[3];
  const float* b_in       = (const float*)d_in[4];
  const float* mlp_ws     = (const float*)d_in[5];
  const float* mlp_bs     = (const float*)d_in[6];
  const float* w_out      = (const float*)d_in[7];
  const float* b_out      = (const float*)d_in[8];

  // ws layout (u16 elems): weights bf16 then two 65536x512 activation buffers
  u16* wInB  = (u16*)d_ws;                 // 262144
  u16* wMlpB = wInB  + 262144;             // 786432 (3 x 512x512)
  u16* wOutB = wMlpB + 786432;             // 524288
  u16* buf0  = wOutB + 524288;             // NTOK*HID
  u16* buf1  = buf0  + (size_t)NTOK * HID; // NTOK*HID

  dim3 blk(256);
  cvt_bf16<<<dim3(262144 / 1024), blk, 0, stream>>>(w_in,   wInB,  262144);
  cvt_bf16<<<dim3(786432 / 1024), blk, 0, stream>>>(mlp_ws, wMlpB, 786432);
  cvt_bf16<<<dim3(524288 / 1024), blk, 0, stream>>>(w_out,  wOutB, 524288);

  feat_kernel<<<dim3(NTOK / 8), blk, 0, stream>>>(chars, byte_embed, hash_tabs, buf0);

  dim3 gblk(512);
  // h0 = relu(features @ w_in^T + b_in)
  gemm256<true,  false, false><<<dim3(2, 256), gblk, 0, stream>>>(
      buf0, wInB, b_in, (const u16*)nullptr, (void*)buf1, NTOK, HID, HID);
  // residual blocks: h = relu(h @ W^T + b) + h
  gemm256<true,  true,  false><<<dim3(2, 256), gblk, 0, stream>>>(
      buf1, wMlpB,          mlp_bs,        buf1, (void*)buf0, NTOK, HID, HID);
  gemm256<true,  true,  false><<<dim3(2, 256), gblk, 0, stream>>>(
      buf0, wMlpB + 262144, mlp_bs + 512,  buf0, (void*)buf1, NTOK, HID, HID);
  gemm256<true,  true,  false><<<dim3(2, 256), gblk, 0, stream>>>(
      buf1, wMlpB + 524288, mlp_bs + 1024, buf1, (void*)buf0, NTOK, HID, HID);
  // logits = h @ w_out^T + b_out  (fp32 out)
  gemm256<false, false, true><<<dim3(4, 256), gblk, 0, stream>>>(
      buf0, wOutB, b_out, (const u16*)nullptr, d_out, NTOK, NVOCAB, HID);
}

// Round 3
// 701.936 us; speedup vs baseline: 1.0564x; 1.0564x over previous
//
#include <hip/hip_runtime.h>
#include <cstdint>
#include <cstddef>

typedef unsigned short u16;
typedef __attribute__((ext_vector_type(8))) short short8;   // 8 x bf16 (4 VGPRs) MFMA A/B frag
typedef __attribute__((ext_vector_type(4))) short short4v;
typedef __attribute__((ext_vector_type(4))) float f32x4;    // MFMA C/D frag

#define NTOK 65536
#define HID 512
#define NVOCAB 1024

// ---------- bf16 helpers (raw-bit, RNE) ----------
__device__ __forceinline__ u16 f2bf(float f) {
  union { float f; uint32_t u; } v; v.f = f;
  uint32_t r = (v.u + 0x7FFFu + ((v.u >> 16) & 1u)) >> 16;
  return (u16)r;
}
__device__ __forceinline__ float bf2f(u16 b) {
  union { uint32_t u; float f; } v; v.u = ((uint32_t)b) << 16;
  return v.f;
}

// async global->LDS, 16B per lane; LDS dest = wave-uniform base + lane*16
__device__ __forceinline__ void gl_lds16(const u16* g, u16* l) {
  __builtin_amdgcn_global_load_lds(
      (const __attribute__((address_space(1))) uint32_t*)g,
      (__attribute__((address_space(3))) uint32_t*)l, 16, 0, 0);
}

// ---------- hash constants (precomputed from reference) ----------
__constant__ uint32_t P24[24] = {
  2654435761u, 2246822519u, 3266489917u, 2028178513u, 1220703125u,
  1610612741u, 805306457u, 402653189u, 3674653429u, 2860486313u,
  1073676287u, 2971215073u, 1500450271u, 3267000013u, 2654435789u,
  4049292737u, 2246822531u, 3266489927u, 2028178519u, 1220703133u,
  1610612743u, 805306459u, 402653191u, 3674653433u};
__constant__ unsigned char OFFS[32][3] = {
  {1,0,0},{2,0,0},{3,0,0},{4,0,0},{5,0,0},{6,0,0},{7,0,0},{8,0,0},
  {1,2,0},{2,3,0},{3,4,0},{1,3,0},{2,4,0},{1,4,0},{1,5,0},{2,5,0},
  {3,5,0},{1,6,0},{2,6,0},{1,7,0},
  {1,2,3},{1,2,4},{1,3,5},{2,3,4},{1,2,5},{1,3,4},{2,4,6},{1,4,7},
  {1,8,0},{1,9,0},{1,10,0},{1,11,0}};
__constant__ unsigned char PLEN[32] = {
  1,1,1,1,1,1,1,1, 2,2,2,2,2,2,2,2,2,2,2,2, 3,3,3,3,3,3,3,3, 2,2,2,2};

// ---------- weight fp32 -> bf16 (4 elems/thread) ----------
__global__ __launch_bounds__(256) void cvt_bf16(const float* __restrict__ src,
                                                u16* __restrict__ dst, int n) {
  int i = (blockIdx.x * 256 + threadIdx.x) * 4;
  if (i < n) {
    float4 f = *(const float4*)(src + i);
    short4v o;
    o[0] = (short)f2bf(f.x); o[1] = (short)f2bf(f.y);
    o[2] = (short)f2bf(f.z); o[3] = (short)f2bf(f.w);
    *(short4v*)(dst + i) = o;
  }
}

// ---------- features: byte-embed + 32 hash embeds -> [NTOK,512] bf16 ----------
// block = 256 threads = 8 tokens x 32 lanes
__global__ __launch_bounds__(256) void feat_kernel(
    const int* __restrict__ chars, const float* __restrict__ byte_embed,
    const float* __restrict__ hash_tables, u16* __restrict__ feat)
{
  const int tid = threadIdx.x;
  const int tl  = tid >> 5;        // token-local 0..7
  const int sub = tid & 31;        // segment / table id
  const size_t t = (size_t)blockIdx.x * 8 + tl;
  const int s = (int)(t & 2047);   // position within sequence
  const int c = chars[t];

  // byte embedding: 8 consecutive floats -> bf16
  {
    const float* src = byte_embed + ((size_t)c << 8) + (sub << 3);
    float4 f0 = ((const float4*)src)[0];
    float4 f1 = ((const float4*)src)[1];
    short8 o;
    o[0]=(short)f2bf(f0.x); o[1]=(short)f2bf(f0.y); o[2]=(short)f2bf(f0.z); o[3]=(short)f2bf(f0.w);
    o[4]=(short)f2bf(f1.x); o[5]=(short)f2bf(f1.y); o[6]=(short)f2bf(f1.z); o[7]=(short)f2bf(f1.w);
    *(short8*)(feat + t * HID + (sub << 3)) = o;
  }

  // hash table `sub`
  {
    const int i = sub;
    const int pl = (int)PLEN[i];
    long long h = 0;
    #pragma unroll
    for (int k = 0; k < 3; ++k) {
      if (k < pl) {
        const int off = (int)OFFS[i][k];
        const long long tok = (s >= off) ? (long long)chars[t - off] : 0ll;
        h ^= tok * (long long)P24[(3 * i + k) % 24];   // tok<2^10, prime<2^32: no ovf
      }
    }
    const int idx_lo = (int)(h & 4095);                // h >= 0
    const long long sp = (long long)P24[(3 * i + pl) % 24];
    // int64 wrap-around multiply (matches jax int64 semantics), arithmetic >>16
    const long long prod = (long long)((unsigned long long)h * (unsigned long long)sp);
    const long long h2 = h ^ (prod >> 16);
    const int idx_hi = (int)(h2 & 4095);               // floored mod == & for pow2
    const float frac = ((float)(int)((h >> 3) & 255) / 255.0f) * 0.4f;
    const float om = 1.0f - frac;

    const float* plo = hash_tables + (((size_t)i << 12) + (size_t)idx_lo) * 8;
    const float* phi = hash_tables + (((size_t)i << 12) + (size_t)idx_hi) * 8;
    float4 a0 = ((const float4*)plo)[0], a1 = ((const float4*)plo)[1];
    float4 b0 = ((const float4*)phi)[0], b1 = ((const float4*)phi)[1];
    short8 o;
    o[0]=(short)f2bf(a0.x*om + b0.x*frac); o[1]=(short)f2bf(a0.y*om + b0.y*frac);
    o[2]=(short)f2bf(a0.z*om + b0.z*frac); o[3]=(short)f2bf(a0.w*om + b0.w*frac);
    o[4]=(short)f2bf(a1.x*om + b1.x*frac); o[5]=(short)f2bf(a1.y*om + b1.y*frac);
    o[6]=(short)f2bf(a1.z*om + b1.z*frac); o[7]=(short)f2bf(a1.w*om + b1.w*frac);
    *(short8*)(feat + t * HID + 256 + (i << 3)) = o;
  }
}

// ---------- fully fused MLP: all 5 layers, h resident in LDS ----------
// Block = 64 tokens, 4 waves, LDS h[64][512] bf16 (64 KB) -> 2 blocks/CU.
// Every layer computed TRANSPOSED: D[n][t] = sum_k W[n][k] h[t][k] via
// mfma(A=W-frag, B=h-frag). C/D gives each lane 4 consecutive features of one
// token -> 8B contiguous ds_write back into row-major h (next layer's B-frag).
// W read per-wave straight from L2 into registers: NO barriers in the K-loop,
// 2 barriers per layer total. h swizzle: elem-chunk index ^= (t&7), applied
// identically at feature-stage (pre-swizzled gl_lds source), epilogue write,
// and fragment read.
__global__ __launch_bounds__(256, 2)
void fused_mlp(const u16* __restrict__ feat,
               const u16* __restrict__ wIn,  const float* __restrict__ bIn,
               const u16* __restrict__ wMlp, const float* __restrict__ bMlp,
               const u16* __restrict__ wOut, const float* __restrict__ bOut,
               float* __restrict__ out)
{
  __shared__ __align__(16) u16 h[64 * 512];
  const int tid  = threadIdx.x;
  const int w    = tid >> 6;        // 0..3 : feature quarter (128 cols of W)
  const int lane = tid & 63;
  const int g    = lane >> 4;       // k-chunk group / D-row group
  const int lr   = lane & 15;       // A: W-row ; B: token ; D: token
  const size_t tok0 = (size_t)blockIdx.x << 6;
  const int swz = (lr & 7) << 3;    // elem-XOR mask (16B granule) for h rows

  // ---- stage features: wave w writes rows it*4+w; lane L sources chunk L^(t&7)
  #pragma unroll
  for (int it = 0; it < 16; ++it) {
    const int tr = (it << 2) + w;
    const u16* src = feat + (tok0 + tr) * HID + ((lane ^ (tr & 7)) << 3);
    gl_lds16(src, &h[tr << 9]);
  }
  __syncthreads();

  f32x4 acc[8][4];

  // GEMM: acc[ni][ti] = W-tile(ni) x h-tile(ti) over K=512. No barriers inside.
  auto gemm = [&](const u16* __restrict__ W) {
    #pragma unroll
    for (int ni = 0; ni < 8; ++ni)
      #pragma unroll
      for (int ti = 0; ti < 4; ++ti) acc[ni][ti] = (f32x4){0.f, 0.f, 0.f, 0.f};
    const u16* Wl = W + (size_t)((w << 7) + lr) * HID + (g << 3);
    #pragma unroll
    for (int kk = 0; kk < 16; ++kk) {
      short8 Wf[8], hf[4];
      #pragma unroll
      for (int ni = 0; ni < 8; ++ni)
        Wf[ni] = *(const short8*)(Wl + (size_t)(ni << 4) * HID + (kk << 5));
      const int kb = ((kk << 5) + (g << 3)) ^ swz;
      #pragma unroll
      for (int ti = 0; ti < 4; ++ti)
        hf[ti] = *(const short8*)&h[(((ti << 4) + lr) << 9) + kb];
      #pragma unroll
      for (int ni = 0; ni < 8; ++ni)
        #pragma unroll
        for (int ti = 0; ti < 4; ++ti)
          acc[ni][ti] = __builtin_amdgcn_mfma_f32_16x16x32_bf16(Wf[ni], hf[ti], acc[ni][ti], 0, 0, 0);
    }
  };

  // hidden-layer epilogue: h[t][n] = relu(acc + b) (+ h_old), in place
  auto epi_h = [&](const float* __restrict__ bias, bool resid) {
    __syncthreads();                     // all GEMM reads of h done blockwide
    #pragma unroll
    for (int ni = 0; ni < 8; ++ni) {
      const int nb = (w << 7) + (ni << 4) + (g << 2);
      const float4 b4 = *(const float4*)(bias + nb);
      #pragma unroll
      for (int ti = 0; ti < 4; ++ti) {
        const int t = (ti << 4) + lr;
        u16* p = &h[(t << 9) + (nb ^ swz)];
        float v0 = fmaxf(acc[ni][ti][0] + b4.x, 0.f);
        float v1 = fmaxf(acc[ni][ti][1] + b4.y, 0.f);
        float v2 = fmaxf(acc[ni][ti][2] + b4.z, 0.f);
        float v3 = fmaxf(acc[ni][ti][3] + b4.w, 0.f);
        if (resid) {                     // lane-private 8B: safe in-place
          const uint2 r2 = *(const uint2*)p;
          v0 += bf2f((u16)(r2.x & 0xffffu)); v1 += bf2f((u16)(r2.x >> 16));
          v2 += bf2f((u16)(r2.y & 0xffffu)); v3 += bf2f((u16)(r2.y >> 16));
        }
        uint2 o;
        o.x = (uint32_t)f2bf(v0) | ((uint32_t)f2bf(v1) << 16);
        o.y = (uint32_t)f2bf(v2) | ((uint32_t)f2bf(v3) << 16);
        *(uint2*)p = o;
      }
    }
    __syncthreads();
  };

  // output epilogue: coalesced float4 logits store (4 consecutive vocab cols)
  auto epi_out = [&](const float* __restrict__ bias, int vb) {
    #pragma unroll
    for (int ni = 0; ni < 8; ++ni) {
      const int nb = (w << 7) + (ni << 4) + (g << 2);
      const float4 b4 = *(const float4*)(bias + vb + nb);
      #pragma unroll
      for (int ti = 0; ti < 4; ++ti) {
        const int t = (ti << 4) + lr;
        float4 o;
        o.x = acc[ni][ti][0] + b4.x;
        o.y = acc[ni][ti][1] + b4.y;
        o.z = acc[ni][ti][2] + b4.z;
        o.w = acc[ni][ti][3] + b4.w;
        *(float4*)(out + (tok0 + t) * NVOCAB + vb + nb) = o;
      }
    }
  };

  // layer 0: h = relu(W_in f + b_in)
  gemm(wIn);
  epi_h(bIn, false);
  // residual blocks: h = relu(W h + b) + h
  #pragma unroll 1
  for (int j = 0; j < 3; ++j) {
    gemm(wMlp + ((size_t)j << 18));
    epi_h(bMlp + (j << 9), true);
  }
  // logits (1024 cols = 2 passes of 512); h is read-only now, no barriers
  gemm(wOut);
  epi_out(bOut, 0);
  gemm(wOut + (size_t)512 * HID);
  epi_out(bOut, 512);
}

extern "C" void kernel_launch(void* const* d_in, const int* in_sizes, int n_in,
                              void* d_out, int out_size, void* d_ws, size_t ws_size,
                              hipStream_t stream) {
  const int*   chars      = (const int*)  d_in[0];
  const float* byte_embed = (const float*)d_in[1];
  const float* hash_tabs  = (const float*)d_in[2];
  const float* w_in       = (const float*)d_in[3];
  const float* b_in       = (const float*)d_in[4];
  const float* mlp_ws     = (const float*)d_in[5];
  const float* mlp_bs     = (const float*)d_in[6];
  const float* w_out      = (const float*)d_in[7];
  const float* b_out      = (const float*)d_in[8];

  // ws layout (u16 elems): bf16 weights, then the feature buffer
  u16* wInB  = (u16*)d_ws;                 // 262144
  u16* wMlpB = wInB  + 262144;             // 786432 (3 x 512x512)
  u16* wOutB = wMlpB + 786432;             // 524288
  u16* buf0  = wOutB + 524288;             // NTOK*HID features

  dim3 blk(256);
  cvt_bf16<<<dim3(262144 / 1024), blk, 0, stream>>>(w_in,   wInB,  262144);
  cvt_bf16<<<dim3(786432 / 1024), blk, 0, stream>>>(mlp_ws, wMlpB, 786432);
  cvt_bf16<<<dim3(524288 / 1024), blk, 0, stream>>>(w_out,  wOutB, 524288);

  feat_kernel<<<dim3(NTOK / 8), blk, 0, stream>>>(chars, byte_embed, hash_tabs, buf0);

  fused_mlp<<<dim3(NTOK / 64), blk, 0, stream>>>(
      buf0, wInB, b_in, wMlpB, mlp_bs, wOutB, b_out, (float*)d_out);
}

// Round 4
// 533.534 us; speedup vs baseline: 1.3899x; 1.3156x over previous
//
#include <hip/hip_runtime.h>
#include <cstdint>
#include <cstddef>

typedef unsigned short u16;
typedef __attribute__((ext_vector_type(8))) short short8;   // 8 x bf16 (4 VGPRs) MFMA A/B frag
typedef __attribute__((ext_vector_type(4))) float f32x4;    // MFMA C/D frag

#define NTOK 65536
#define HID 512
#define NVOCAB 1024

// ---------- bf16 helpers (raw-bit, RNE) ----------
__device__ __forceinline__ u16 f2bf(float f) {
  union { float f; uint32_t u; } v; v.f = f;
  uint32_t r = (v.u + 0x7FFFu + ((v.u >> 16) & 1u)) >> 16;
  return (u16)r;
}
__device__ __forceinline__ float bf2f(u16 b) {
  union { uint32_t u; float f; } v; v.u = ((uint32_t)b) << 16;
  return v.f;
}

// ---------- hash constants (precomputed from reference) ----------
__constant__ uint32_t P24[24] = {
  2654435761u, 2246822519u, 3266489917u, 2028178513u, 1220703125u,
  1610612741u, 805306457u, 402653189u, 3674653429u, 2860486313u,
  1073676287u, 2971215073u, 1500450271u, 3267000013u, 2654435789u,
  4049292737u, 2246822531u, 3266489927u, 2028178519u, 1220703133u,
  1610612743u, 805306459u, 402653191u, 3674653433u};
__constant__ unsigned char OFFS[32][3] = {
  {1,0,0},{2,0,0},{3,0,0},{4,0,0},{5,0,0},{6,0,0},{7,0,0},{8,0,0},
  {1,2,0},{2,3,0},{3,4,0},{1,3,0},{2,4,0},{1,4,0},{1,5,0},{2,5,0},
  {3,5,0},{1,6,0},{2,6,0},{1,7,0},
  {1,2,3},{1,2,4},{1,3,5},{2,3,4},{1,2,5},{1,3,4},{2,4,6},{1,4,7},
  {1,8,0},{1,9,0},{1,10,0},{1,11,0}};
__constant__ unsigned char PLEN[32] = {
  1,1,1,1,1,1,1,1, 2,2,2,2,2,2,2,2,2,2,2,2, 3,3,3,3,3,3,3,3, 2,2,2,2};

// ---------- weight repack: six 512x512 fp32 layer-matrices -> bf16 fragment
// order. dst 16B chunk c within layer: lane=c&63, ni=(c>>6)&3, kk=(c>>8)&15,
// w=c>>12. Source element block: row = w*64+ni*16+(lane&15),
// col = kk*32+(lane>>4)*8 .. +8. A wave's Wf load then reads 1024 CONTIGUOUS
// bytes (base + lane*16) — perfectly coalesced sequential L2 stream.
__global__ __launch_bounds__(256) void pack_w(
    const float* __restrict__ w_in, const float* __restrict__ mlp_ws,
    const float* __restrict__ w_out, u16* __restrict__ Wp)
{
  const int gid  = blockIdx.x * 256 + threadIdx.x;   // 0..196607
  const int L    = gid >> 15;                        // layer 0..5
  const int c    = gid & 32767;
  const int lane = c & 63;
  const int ni   = (c >> 6) & 3;
  const int kk   = (c >> 8) & 15;
  const int w    = c >> 12;
  const float* base =
      (L == 0) ? w_in :
      (L <= 3) ? mlp_ws + (size_t)(L - 1) * 262144 :
                 w_out  + (size_t)(L - 4) * 262144;
  const int row = (w << 6) + (ni << 4) + (lane & 15);
  const int col = (kk << 5) + ((lane >> 4) << 3);
  const float* s = base + (size_t)row * 512 + col;
  float4 f0 = ((const float4*)s)[0];
  float4 f1 = ((const float4*)s)[1];
  short8 o;
  o[0]=(short)f2bf(f0.x); o[1]=(short)f2bf(f0.y); o[2]=(short)f2bf(f0.z); o[3]=(short)f2bf(f0.w);
  o[4]=(short)f2bf(f1.x); o[5]=(short)f2bf(f1.y); o[6]=(short)f2bf(f1.z); o[7]=(short)f2bf(f1.w);
  *(short8*)(Wp + (size_t)gid * 8) = o;
}

// ---------- fully fused: features + all 5 layers, h resident in LDS ----------
// Block = 128 tokens, 8 waves (512 thr), LDS h[128][512] bf16 = 128 KB.
// Feature phase computes byte-embed + 32 hash embeds straight into swizzled
// LDS (no feat round-trip through HBM). Each layer computed TRANSPOSED:
// D[n][t] = sum_k W[n][k] h[t][k], wave w owns W-rows [w*64,(w+1)*64).
// W streams from the packed fragment-order table (coalesced, L2-resident,
// halved traffic vs 64-token blocks). h swizzle: 16B-chunk index ^= (t&7),
// applied identically at feature write, epilogue write, and fragment read.
__global__ __launch_bounds__(512, 2)
void fused_all(const int* __restrict__ chars, const float* __restrict__ byte_embed,
               const float* __restrict__ hash_tables, const u16* __restrict__ Wp,
               const float* __restrict__ bIn, const float* __restrict__ bMlp,
               const float* __restrict__ bOut, float* __restrict__ out)
{
  __shared__ __align__(16) u16 hbuf[128 * 512];   // 128 KiB
  const int tid  = threadIdx.x;
  const int w    = tid >> 6;        // wave 0..7 : W-row block of 64
  const int lane = tid & 63;
  const int g    = lane >> 4;       // k-chunk group / D-row group
  const int lr   = lane & 15;       // A: W-row ; B/D: token
  const size_t tok0 = (size_t)blockIdx.x << 7;
  const int swz = (lr & 7) << 3;    // elem-XOR mask (16B granule) for h rows

  // ================= feature phase: 16 tokens x 32 tables, 8 passes =========
  {
    const int sub = tid & 31;       // table id / byte-chunk id
    const int tl  = tid >> 5;       // 0..15
    const int i   = sub;
    const int pl  = (int)PLEN[i];
    #pragma unroll 1
    for (int pass = 0; pass < 8; ++pass) {
      const int tr = (pass << 4) + tl;           // token row 0..127
      const size_t t = tok0 + tr;
      const int pos = (int)(t & 2047);           // position within sequence
      const int c = chars[t];
      const int sw = (tr & 7) << 3;              // write-side swizzle (elems)
      // byte embedding -> chunks 0..31
      {
        const float* src = byte_embed + ((size_t)c << 8) + (sub << 3);
        float4 f0 = ((const float4*)src)[0];
        float4 f1 = ((const float4*)src)[1];
        short8 o;
        o[0]=(short)f2bf(f0.x); o[1]=(short)f2bf(f0.y); o[2]=(short)f2bf(f0.z); o[3]=(short)f2bf(f0.w);
        o[4]=(short)f2bf(f1.x); o[5]=(short)f2bf(f1.y); o[6]=(short)f2bf(f1.z); o[7]=(short)f2bf(f1.w);
        *(short8*)&hbuf[(tr << 9) + (((sub << 3)) ^ sw)] = o;
      }
      // hash table sub -> chunks 32..63
      {
        long long hv = 0;
        #pragma unroll
        for (int k = 0; k < 3; ++k) {
          if (k < pl) {
            const int off = (int)OFFS[i][k];
            const long long tok = (pos >= off) ? (long long)chars[t - off] : 0ll;
            hv ^= tok * (long long)P24[(3 * i + k) % 24];  // tok<2^10, prime<2^32: no ovf
          }
        }
        const int idx_lo = (int)(hv & 4095);               // hv >= 0
        const long long p2 = (long long)P24[(3 * i + pl) % 24];
        // int64 wrap-around multiply (matches jax int64), arithmetic >>16
        const long long prod = (long long)((unsigned long long)hv * (unsigned long long)p2);
        const long long h2 = hv ^ (prod >> 16);
        const int idx_hi = (int)(h2 & 4095);
        const float frac = ((float)(int)((hv >> 3) & 255) / 255.0f) * 0.4f;
        const float om = 1.0f - frac;
        const float* plo = hash_tables + (((size_t)i << 12) + (size_t)idx_lo) * 8;
        const float* phi = hash_tables + (((size_t)i << 12) + (size_t)idx_hi) * 8;
        float4 a0 = ((const float4*)plo)[0], a1 = ((const float4*)plo)[1];
        float4 b0 = ((const float4*)phi)[0], b1 = ((const float4*)phi)[1];
        short8 o;
        o[0]=(short)f2bf(a0.x*om + b0.x*frac); o[1]=(short)f2bf(a0.y*om + b0.y*frac);
        o[2]=(short)f2bf(a0.z*om + b0.z*frac); o[3]=(short)f2bf(a0.w*om + b0.w*frac);
        o[4]=(short)f2bf(a1.x*om + b1.x*frac); o[5]=(short)f2bf(a1.y*om + b1.y*frac);
        o[6]=(short)f2bf(a1.z*om + b1.z*frac); o[7]=(short)f2bf(a1.w*om + b1.w*frac);
        *(short8*)&hbuf[(tr << 9) + (((256 + (sub << 3))) ^ sw)] = o;
      }
    }
  }
  __syncthreads();

  f32x4 acc[4][8];

  // GEMM: acc[ni][ti] = Wp-layer-L rows [w*64+ni*16 ..] x h-tokens [ti*16 ..]
  // over K=512. W from packed global (coalesced stream), h from LDS. No
  // barriers inside.
  auto gemm = [&](int L) {
    #pragma unroll
    for (int ni = 0; ni < 4; ++ni)
      #pragma unroll
      for (int ti = 0; ti < 8; ++ti) acc[ni][ti] = (f32x4){0.f, 0.f, 0.f, 0.f};
    const u16* Wl = Wp + (size_t)L * 262144 + (w << 15) + (lane << 3);
    #pragma unroll
    for (int kk = 0; kk < 16; ++kk) {
      short8 Wf[4], hf[8];
      #pragma unroll
      for (int ni = 0; ni < 4; ++ni)
        Wf[ni] = *(const short8*)(Wl + (kk << 11) + (ni << 9));
      const int kb = ((kk << 5) + (g << 3)) ^ swz;
      #pragma unroll
      for (int ti = 0; ti < 8; ++ti)
        hf[ti] = *(const short8*)&hbuf[(((ti << 4) + lr) << 9) + kb];
      #pragma unroll
      for (int ni = 0; ni < 4; ++ni)
        #pragma unroll
        for (int ti = 0; ti < 8; ++ti)
          acc[ni][ti] = __builtin_amdgcn_mfma_f32_16x16x32_bf16(Wf[ni], hf[ti], acc[ni][ti], 0, 0, 0);
    }
  };

  // hidden-layer epilogue: h[t][n] = relu(acc + b) (+ h_old), in place
  auto epi_h = [&](const float* __restrict__ bias, bool resid) {
    __syncthreads();                     // all GEMM reads of h done blockwide
    #pragma unroll
    for (int ni = 0; ni < 4; ++ni) {
      const int nb = (w << 6) + (ni << 4) + (g << 2);
      const float4 b4 = *(const float4*)(bias + nb);
      #pragma unroll
      for (int ti = 0; ti < 8; ++ti) {
        const int t = (ti << 4) + lr;
        u16* p = &hbuf[(t << 9) + (nb ^ swz)];
        float v0 = fmaxf(acc[ni][ti][0] + b4.x, 0.f);
        float v1 = fmaxf(acc[ni][ti][1] + b4.y, 0.f);
        float v2 = fmaxf(acc[ni][ti][2] + b4.z, 0.f);
        float v3 = fmaxf(acc[ni][ti][3] + b4.w, 0.f);
        if (resid) {                     // lane-private 8B: safe in-place
          const uint2 r2 = *(const uint2*)p;
          v0 += bf2f((u16)(r2.x & 0xffffu)); v1 += bf2f((u16)(r2.x >> 16));
          v2 += bf2f((u16)(r2.y & 0xffffu)); v3 += bf2f((u16)(r2.y >> 16));
        }
        uint2 o;
        o.x = (uint32_t)f2bf(v0) | ((uint32_t)f2bf(v1) << 16);
        o.y = (uint32_t)f2bf(v2) | ((uint32_t)f2bf(v3) << 16);
        *(uint2*)p = o;
      }
    }
    __syncthreads();
  };

  // output epilogue: coalesced float4 logits store (4 consecutive vocab cols;
  // g=0..3 of one lr fill a full 64B line)
  auto epi_out = [&](const float* __restrict__ bias, int vb) {
    #pragma unroll
    for (int ni = 0; ni < 4; ++ni) {
      const int nb = (w << 6) + (ni << 4) + (g << 2);
      const float4 b4 = *(const float4*)(bias + nb);
      #pragma unroll
      for (int ti = 0; ti < 8; ++ti) {
        const int t = (ti << 4) + lr;
        float4 o;
        o.x = acc[ni][ti][0] + b4.x;
        o.y = acc[ni][ti][1] + b4.y;
        o.z = acc[ni][ti][2] + b4.z;
        o.w = acc[ni][ti][3] + b4.w;
        *(float4*)(out + (tok0 + t) * NVOCAB + vb + nb) = o;
      }
    }
  };

  // layer 0: h = relu(W_in f + b_in)
  gemm(0); epi_h(bIn, false);
  // residual blocks: h = relu(W h + b) + h
  gemm(1); epi_h(bMlp,        true);
  gemm(2); epi_h(bMlp + 512,  true);
  gemm(3); epi_h(bMlp + 1024, true);
  // logits (1024 cols = layers 4,5); h read-only now, no barriers needed
  gemm(4); epi_out(bOut,       0);
  gemm(5); epi_out(bOut + 512, 512);
}

extern "C" void kernel_launch(void* const* d_in, const int* in_sizes, int n_in,
                              void* d_out, int out_size, void* d_ws, size_t ws_size,
                              hipStream_t stream) {
  const int*   chars      = (const int*)  d_in[0];
  const float* byte_embed = (const float*)d_in[1];
  const float* hash_tabs  = (const float*)d_in[2];
  const float* w_in       = (const float*)d_in[3];
  const float* b_in       = (const float*)d_in[4];
  const float* mlp_ws     = (const float*)d_in[5];
  const float* mlp_bs     = (const float*)d_in[6];
  const float* w_out      = (const float*)d_in[7];
  const float* b_out      = (const float*)d_in[8];

  // ws: packed weights, 6 layers x 512KB bf16 = 3 MB
  u16* Wp = (u16*)d_ws;

  pack_w<<<dim3(768), dim3(256), 0, stream>>>(w_in, mlp_ws, w_out, Wp);

  fused_all<<<dim3(NTOK / 128), dim3(512), 0, stream>>>(
      chars, byte_embed, hash_tabs, Wp, b_in, mlp_bs, b_out, (float*)d_out);
}

// Round 5
// 525.103 us; speedup vs baseline: 1.4122x; 1.0161x over previous
//
#include <hip/hip_runtime.h>
#include <cstdint>
#include <cstddef>

typedef unsigned short u16;
typedef __attribute__((ext_vector_type(8))) short short8;   // 8 x bf16 (4 VGPRs) MFMA A/B frag
typedef __attribute__((ext_vector_type(4))) float f32x4;    // MFMA C/D frag

#define NTOK 65536
#define HID 512
#define NVOCAB 1024

// ---------- bf16 helpers (raw-bit, RNE) ----------
__device__ __forceinline__ u16 f2bf(float f) {
  union { float f; uint32_t u; } v; v.f = f;
  uint32_t r = (v.u + 0x7FFFu + ((v.u >> 16) & 1u)) >> 16;
  return (u16)r;
}
__device__ __forceinline__ float bf2f(u16 b) {
  union { uint32_t u; float f; } v; v.u = ((uint32_t)b) << 16;
  return v.f;
}

// ---------- hash constants (precomputed from reference) ----------
__constant__ uint32_t P24[24] = {
  2654435761u, 2246822519u, 3266489917u, 2028178513u, 1220703125u,
  1610612741u, 805306457u, 402653189u, 3674653429u, 2860486313u,
  1073676287u, 2971215073u, 1500450271u, 3267000013u, 2654435789u,
  4049292737u, 2246822531u, 3266489927u, 2028178519u, 1220703133u,
  1610612743u, 805306459u, 402653191u, 3674653433u};
__constant__ unsigned char OFFS[32][3] = {
  {1,0,0},{2,0,0},{3,0,0},{4,0,0},{5,0,0},{6,0,0},{7,0,0},{8,0,0},
  {1,2,0},{2,3,0},{3,4,0},{1,3,0},{2,4,0},{1,4,0},{1,5,0},{2,5,0},
  {3,5,0},{1,6,0},{2,6,0},{1,7,0},
  {1,2,3},{1,2,4},{1,3,5},{2,3,4},{1,2,5},{1,3,4},{2,4,6},{1,4,7},
  {1,8,0},{1,9,0},{1,10,0},{1,11,0}};
__constant__ unsigned char PLEN[32] = {
  1,1,1,1,1,1,1,1, 2,2,2,2,2,2,2,2,2,2,2,2, 3,3,3,3,3,3,3,3, 2,2,2,2};

// ---------- weight repack: six 512x512 fp32 layer-matrices -> bf16 fragment
// order. dst 16B chunk c within layer: lane=c&63, ni=(c>>6)&3, kk=(c>>8)&15,
// w=c>>12. Source element block: row = w*64+ni*16+(lane&15),
// col = kk*32+(lane>>4)*8 .. +8. A wave's Wf load then reads 1024 CONTIGUOUS
// bytes (base + lane*16) — perfectly coalesced sequential L2 stream.
__global__ __launch_bounds__(256) void pack_w(
    const float* __restrict__ w_in, const float* __restrict__ mlp_ws,
    const float* __restrict__ w_out, u16* __restrict__ Wp)
{
  const int gid  = blockIdx.x * 256 + threadIdx.x;   // 0..196607
  const int L    = gid >> 15;                        // layer 0..5
  const int c    = gid & 32767;
  const int lane = c & 63;
  const int ni   = (c >> 6) & 3;
  const int kk   = (c >> 8) & 15;
  const int w    = c >> 12;
  const float* base =
      (L == 0) ? w_in :
      (L <= 3) ? mlp_ws + (size_t)(L - 1) * 262144 :
                 w_out  + (size_t)(L - 4) * 262144;
  const int row = (w << 6) + (ni << 4) + (lane & 15);
  const int col = (kk << 5) + ((lane >> 4) << 3);
  const float* s = base + (size_t)row * 512 + col;
  float4 f0 = ((const float4*)s)[0];
  float4 f1 = ((const float4*)s)[1];
  short8 o;
  o[0]=(short)f2bf(f0.x); o[1]=(short)f2bf(f0.y); o[2]=(short)f2bf(f0.z); o[3]=(short)f2bf(f0.w);
  o[4]=(short)f2bf(f1.x); o[5]=(short)f2bf(f1.y); o[6]=(short)f2bf(f1.z); o[7]=(short)f2bf(f1.w);
  *(short8*)(Wp + (size_t)gid * 8) = o;
}

// ---------- fully fused: features + all 5 layers, h resident in LDS ----------
// Block = 64 tokens, 8 waves (512 thr), LDS h[64][512] bf16 = 64 KB
// -> 2 blocks/CU: feature-phase gather latency and epilogue barriers of one
// block overlap GEMMs of the co-resident block (the R4 1-block/CU config had
// MfmaUtil 30% with the matrix pipe idle through both serial phases).
// Wave w owns W-rows [w*64,(w+1)*64) (ni=0..3), all 64 tokens (ti=0..3):
// acc 4x4 = 64 VGPR; __launch_bounds__(512,4) caps VGPR at 128 so both
// blocks' 16 waves stay resident. W streams from the packed fragment-order
// table (coalesced sequential L2). h swizzle: 16B-chunk index ^= (t&7) at
// feature write, epilogue write, and fragment read.
__global__ __launch_bounds__(512, 4)
void fused_all(const int* __restrict__ chars, const float* __restrict__ byte_embed,
               const float* __restrict__ hash_tables, const u16* __restrict__ Wp,
               const float* __restrict__ bIn, const float* __restrict__ bMlp,
               const float* __restrict__ bOut, float* __restrict__ out)
{
  __shared__ __align__(16) u16 hbuf[64 * 512];   // 64 KiB
  const int tid  = threadIdx.x;
  const int w    = tid >> 6;        // wave 0..7 : W-row block of 64
  const int lane = tid & 63;
  const int g    = lane >> 4;       // k-chunk group / D-row group
  const int lr   = lane & 15;       // A: W-row ; B/D: token
  const size_t tok0 = (size_t)blockIdx.x << 6;
  const int swz = (lr & 7) << 3;    // elem-XOR mask (16B granule) for h rows

  // ================= feature phase: 16 tokens x 32 tables, 4 passes =========
  {
    const int sub = tid & 31;       // table id / byte-chunk id
    const int tl  = tid >> 5;       // 0..15
    const int i   = sub;
    const int pl  = (int)PLEN[i];
    #pragma unroll 1
    for (int pass = 0; pass < 4; ++pass) {
      const int tr = (pass << 4) + tl;           // token row 0..63
      const size_t t = tok0 + tr;
      const int pos = (int)(t & 2047);           // position within sequence
      const int c = chars[t];
      const int sw = (tr & 7) << 3;              // write-side swizzle (elems)
      // byte embedding -> chunks 0..31
      {
        const float* src = byte_embed + ((size_t)c << 8) + (sub << 3);
        float4 f0 = ((const float4*)src)[0];
        float4 f1 = ((const float4*)src)[1];
        short8 o;
        o[0]=(short)f2bf(f0.x); o[1]=(short)f2bf(f0.y); o[2]=(short)f2bf(f0.z); o[3]=(short)f2bf(f0.w);
        o[4]=(short)f2bf(f1.x); o[5]=(short)f2bf(f1.y); o[6]=(short)f2bf(f1.z); o[7]=(short)f2bf(f1.w);
        *(short8*)&hbuf[(tr << 9) + (((sub << 3)) ^ sw)] = o;
      }
      // hash table sub -> chunks 32..63
      {
        long long hv = 0;
        #pragma unroll
        for (int k = 0; k < 3; ++k) {
          if (k < pl) {
            const int off = (int)OFFS[i][k];
            const long long tok = (pos >= off) ? (long long)chars[t - off] : 0ll;
            hv ^= tok * (long long)P24[(3 * i + k) % 24];  // tok<2^10, prime<2^32: no ovf
          }
        }
        const int idx_lo = (int)(hv & 4095);               // hv >= 0
        const long long p2 = (long long)P24[(3 * i + pl) % 24];
        // int64 wrap-around multiply (matches jax int64), arithmetic >>16
        const long long prod = (long long)((unsigned long long)hv * (unsigned long long)p2);
        const long long h2 = hv ^ (prod >> 16);
        const int idx_hi = (int)(h2 & 4095);
        const float frac = ((float)(int)((hv >> 3) & 255) / 255.0f) * 0.4f;
        const float om = 1.0f - frac;
        const float* plo = hash_tables + (((size_t)i << 12) + (size_t)idx_lo) * 8;
        const float* phi = hash_tables + (((size_t)i << 12) + (size_t)idx_hi) * 8;
        float4 a0 = ((const float4*)plo)[0], a1 = ((const float4*)plo)[1];
        float4 b0 = ((const float4*)phi)[0], b1 = ((const float4*)phi)[1];
        short8 o;
        o[0]=(short)f2bf(a0.x*om + b0.x*frac); o[1]=(short)f2bf(a0.y*om + b0.y*frac);
        o[2]=(short)f2bf(a0.z*om + b0.z*frac); o[3]=(short)f2bf(a0.w*om + b0.w*frac);
        o[4]=(short)f2bf(a1.x*om + b1.x*frac); o[5]=(short)f2bf(a1.y*om + b1.y*frac);
        o[6]=(short)f2bf(a1.z*om + b1.z*frac); o[7]=(short)f2bf(a1.w*om + b1.w*frac);
        *(short8*)&hbuf[(tr << 9) + (((256 + (sub << 3))) ^ sw)] = o;
      }
    }
  }
  __syncthreads();

  f32x4 acc[4][4];

  // GEMM: acc[ni][ti] = Wp-layer-L rows [w*64+ni*16 ..] x h-tokens [ti*16 ..]
  // over K=512. W from packed global (coalesced stream), h from LDS. No
  // barriers inside.
  auto gemm = [&](int L) {
    #pragma unroll
    for (int ni = 0; ni < 4; ++ni)
      #pragma unroll
      for (int ti = 0; ti < 4; ++ti) acc[ni][ti] = (f32x4){0.f, 0.f, 0.f, 0.f};
    const u16* Wl = Wp + (size_t)L * 262144 + (w << 15) + (lane << 3);
    #pragma unroll
    for (int kk = 0; kk < 16; ++kk) {
      short8 Wf[4], hf[4];
      #pragma unroll
      for (int ni = 0; ni < 4; ++ni)
        Wf[ni] = *(const short8*)(Wl + (kk << 11) + (ni << 9));
      const int kb = ((kk << 5) + (g << 3)) ^ swz;
      #pragma unroll
      for (int ti = 0; ti < 4; ++ti)
        hf[ti] = *(const short8*)&hbuf[(((ti << 4) + lr) << 9) + kb];
      #pragma unroll
      for (int ni = 0; ni < 4; ++ni)
        #pragma unroll
        for (int ti = 0; ti < 4; ++ti)
          acc[ni][ti] = __builtin_amdgcn_mfma_f32_16x16x32_bf16(Wf[ni], hf[ti], acc[ni][ti], 0, 0, 0);
    }
  };

  // hidden-layer epilogue: h[t][n] = relu(acc + b) (+ h_old), in place
  auto epi_h = [&](const float* __restrict__ bias, bool resid) {
    __syncthreads();                     // all GEMM reads of h done blockwide
    #pragma unroll
    for (int ni = 0; ni < 4; ++ni) {
      const int nb = (w << 6) + (ni << 4) + (g << 2);
      const float4 b4 = *(const float4*)(bias + nb);
      #pragma unroll
      for (int ti = 0; ti < 4; ++ti) {
        const int t = (ti << 4) + lr;
        u16* p = &hbuf[(t << 9) + (nb ^ swz)];
        float v0 = fmaxf(acc[ni][ti][0] + b4.x, 0.f);
        float v1 = fmaxf(acc[ni][ti][1] + b4.y, 0.f);
        float v2 = fmaxf(acc[ni][ti][2] + b4.z, 0.f);
        float v3 = fmaxf(acc[ni][ti][3] + b4.w, 0.f);
        if (resid) {                     // lane-private 8B: safe in-place
          const uint2 r2 = *(const uint2*)p;
          v0 += bf2f((u16)(r2.x & 0xffffu)); v1 += bf2f((u16)(r2.x >> 16));
          v2 += bf2f((u16)(r2.y & 0xffffu)); v3 += bf2f((u16)(r2.y >> 16));
        }
        uint2 o;
        o.x = (uint32_t)f2bf(v0) | ((uint32_t)f2bf(v1) << 16);
        o.y = (uint32_t)f2bf(v2) | ((uint32_t)f2bf(v3) << 16);
        *(uint2*)p = o;
      }
    }
    __syncthreads();
  };

  // output epilogue: coalesced float4 logits store (4 consecutive vocab cols;
  // g=0..3 of one lr fill a full 64B span per row)
  auto epi_out = [&](const float* __restrict__ bias, int vb) {
    #pragma unroll
    for (int ni = 0; ni < 4; ++ni) {
      const int nb = (w << 6) + (ni << 4) + (g << 2);
      const float4 b4 = *(const float4*)(bias + nb);
      #pragma unroll
      for (int ti = 0; ti < 4; ++ti) {
        const int t = (ti << 4) + lr;
        float4 o;
        o.x = acc[ni][ti][0] + b4.x;
        o.y = acc[ni][ti][1] + b4.y;
        o.z = acc[ni][ti][2] + b4.z;
        o.w = acc[ni][ti][3] + b4.w;
        *(float4*)(out + (tok0 + t) * NVOCAB + vb + nb) = o;
      }
    }
  };

  // layer 0: h = relu(W_in f + b_in)
  gemm(0); epi_h(bIn, false);
  // residual blocks: h = relu(W h + b) + h
  gemm(1); epi_h(bMlp,        true);
  gemm(2); epi_h(bMlp + 512,  true);
  gemm(3); epi_h(bMlp + 1024, true);
  // logits (1024 cols = layers 4,5); h read-only now, no barriers needed
  gemm(4); epi_out(bOut,       0);
  gemm(5); epi_out(bOut + 512, 512);
}

extern "C" void kernel_launch(void* const* d_in, const int* in_sizes, int n_in,
                              void* d_out, int out_size, void* d_ws, size_t ws_size,
                              hipStream_t stream) {
  const int*   chars      = (const int*)  d_in[0];
  const float* byte_embed = (const float*)d_in[1];
  const float* hash_tabs  = (const float*)d_in[2];
  const float* w_in       = (const float*)d_in[3];
  const float* b_in       = (const float*)d_in[4];
  const float* mlp_ws     = (const float*)d_in[5];
  const float* mlp_bs     = (const float*)d_in[6];
  const float* w_out      = (const float*)d_in[7];
  const float* b_out      = (const float*)d_in[8];

  // ws: packed weights, 6 layers x 512KB bf16 = 3 MB
  u16* Wp = (u16*)d_ws;

  pack_w<<<dim3(768), dim3(256), 0, stream>>>(w_in, mlp_ws, w_out, Wp);

  fused_all<<<dim3(NTOK / 64), dim3(512), 0, stream>>>(
      chars, byte_embed, hash_tabs, Wp, b_in, mlp_bs, b_out, (float*)d_out);
}